// Round 1
// baseline (18793.568 us; speedup 1.0000x reference)
//
#include <hip/hip_runtime.h>
#include <hip/hip_fp16.h>

#define BB 64
#define TT 2048
#define DD 256
#define HH 256

typedef _Float16 h2 __attribute__((ext_vector_type(2)));
typedef _Float16 f16x8 __attribute__((ext_vector_type(8)));

union V8 { f16x8 v; h2 p[4]; };

__device__ __forceinline__ float sigm(float v) {
    return __builtin_amdgcn_rcpf(1.f + __expf(-v));
}
__device__ __forceinline__ float tanh_f(float v) {
    float e = __expf(2.f * v);
    return 1.f - 2.f * __builtin_amdgcn_rcpf(e + 1.f);
}

// Pack W [256][1024] f32 (row-major, k-major) into f16 layout [k/8][1024][8]:
// out[((k>>3)*1024 + j)*8 + (k&7)] = (f16) w[k*1024 + j]
__global__ void pack_w(const float* __restrict__ w, _Float16* __restrict__ o) {
    int idx = blockIdx.x * 256 + threadIdx.x;     // idx = k*1024 + j, 0..262143
    int j = idx & 1023;
    int k = idx >> 10;
    o[(((k >> 3) * 1024) + j) * 8 + (k & 7)] = (_Float16)w[idx];
}

__global__ __launch_bounds__(256) void lstm_kernel(
    const float* __restrict__ x,      // [B, T, D] f32
    const float* __restrict__ b_xh,   // [1024]
    const float* __restrict__ b_hh,   // [1024]
    const _Float16* __restrict__ Wx,  // packed [32][1024][8]
    const _Float16* __restrict__ Wh,  // packed [32][1024][8]
    float* __restrict__ out)          // [B*T*H] ++ h_fin[2,B,H] ++ c_fin[2,B,H]
{
    __shared__ _Float16 x_lds[DD];
    __shared__ _Float16 h0_lds[HH];
    __shared__ _Float16 h1_lds[HH];

    const int tid = threadIdx.x;
    const int b = blockIdx.x;

    // biases for this thread's 4 gate columns (i,f,g,o of h-index tid)
    float bx0 = b_xh[tid], bx1 = b_xh[tid + 256], bx2 = b_xh[tid + 512], bx3 = b_xh[tid + 768];
    float bh0 = b_hh[tid], bh1 = b_hh[tid + 256], bh2 = b_hh[tid + 512], bh3 = b_hh[tid + 768];

    // init state
    x_lds[tid]  = (_Float16)x[(size_t)b * TT * DD + tid];  // x_0
    h0_lds[tid] = (_Float16)0.f;
    h1_lds[tid] = (_Float16)0.f;
    float c0 = 0.f, c1 = 0.f;
    float h0keep = 0.f, h1keep = 0.f;

    const f16x8* __restrict__ wxp = (const f16x8*)Wx;
    const f16x8* __restrict__ whp = (const f16x8*)Wh;

    __syncthreads();

    for (int p = 0; p <= TT; ++p) {
        // prefetch x_{p+1} (zero for the pipeline-drain phase)
        float xn = 0.f;
        if (p + 1 < TT) xn = x[(size_t)b * TT * DD + (size_t)(p + 1) * DD + tid];

        float dx0 = 0.f, dx1 = 0.f, dx2 = 0.f, dx3 = 0.f;
        float d00 = 0.f, d01 = 0.f, d02 = 0.f, d03 = 0.f;
        float d10 = 0.f, d11 = 0.f, d12 = 0.f, d13 = 0.f;

        const f16x8* wxt = wxp + tid;
        const f16x8* wht = whp + tid;

#pragma unroll 2
        for (int kk = 0; kk < 32; ++kk) {
            V8 xv, h0v, h1v;
            xv.v  = *(const f16x8*)&x_lds[kk * 8];
            h0v.v = *(const f16x8*)&h0_lds[kk * 8];
            h1v.v = *(const f16x8*)&h1_lds[kk * 8];

            V8 wxa, wxb, wxc, wxd, wha, whb, whc, whd;
            wxa.v = wxt[kk * 1024 + 0];
            wxb.v = wxt[kk * 1024 + 256];
            wxc.v = wxt[kk * 1024 + 512];
            wxd.v = wxt[kk * 1024 + 768];
            wha.v = wht[kk * 1024 + 0];
            whb.v = wht[kk * 1024 + 256];
            whc.v = wht[kk * 1024 + 512];
            whd.v = wht[kk * 1024 + 768];

#pragma unroll
            for (int r = 0; r < 4; ++r) {
                dx0 = __builtin_amdgcn_fdot2(xv.p[r],  wxa.p[r], dx0, false);
                dx1 = __builtin_amdgcn_fdot2(xv.p[r],  wxb.p[r], dx1, false);
                dx2 = __builtin_amdgcn_fdot2(xv.p[r],  wxc.p[r], dx2, false);
                dx3 = __builtin_amdgcn_fdot2(xv.p[r],  wxd.p[r], dx3, false);
                d00 = __builtin_amdgcn_fdot2(h0v.p[r], wha.p[r], d00, false);
                d01 = __builtin_amdgcn_fdot2(h0v.p[r], whb.p[r], d01, false);
                d02 = __builtin_amdgcn_fdot2(h0v.p[r], whc.p[r], d02, false);
                d03 = __builtin_amdgcn_fdot2(h0v.p[r], whd.p[r], d03, false);
                d10 = __builtin_amdgcn_fdot2(h1v.p[r], wha.p[r], d10, false);
                d11 = __builtin_amdgcn_fdot2(h1v.p[r], whb.p[r], d11, false);
                d12 = __builtin_amdgcn_fdot2(h1v.p[r], whc.p[r], d12, false);
                d13 = __builtin_amdgcn_fdot2(h1v.p[r], whd.p[r], d13, false);
            }
        }

        // ----- layer 0, step p (skip at drain phase p==TT) -----
        float h0n = h0keep;
        if (p < TT) {
            float gi = bx0 + bh0 + dx0 + d00;
            float gf = bx1 + bh1 + dx1 + d01;
            float gg = bx2 + bh2 + dx2 + d02;
            float go = bx3 + bh3 + dx3 + d03;
            c0 = c0 * sigm(gf) + sigm(gi) * tanh_f(gg);
            h0n = sigm(go) * tanh_f(c0);
            h0keep = h0n;
        }

        // ----- layer 1, step p-1 (skip at fill phase p==0) -----
        float h1n = 0.f;
        if (p > 0) {
            float gi = 2.f * bh0 + d00 + d10;
            float gf = 2.f * bh1 + d01 + d11;
            float gg = 2.f * bh2 + d02 + d12;
            float go = 2.f * bh3 + d03 + d13;
            c1 = c1 * sigm(gf) + sigm(gi) * tanh_f(gg);
            h1n = sigm(go) * tanh_f(c1);
            h1keep = h1n;
            out[(size_t)b * TT * HH + (size_t)(p - 1) * HH + tid] = h1n;
        }

        __syncthreads();  // all dot-reads of x/h LDS complete

        if (p < TT) {
            x_lds[tid]  = (_Float16)xn;   // x_{p+1}
            h0_lds[tid] = (_Float16)h0n;  // h0(p)
        }
        if (p > 0) {
            h1_lds[tid] = (_Float16)h1n;  // h1(p-1)
        }

        __syncthreads();  // LDS state ready for next phase
    }

    // final states: h_fin[2,B,H] then c_fin[2,B,H]
    size_t base = (size_t)BB * TT * HH;
    out[base + (size_t)b * HH + tid]                       = h0keep;
    out[base + (size_t)BB * HH + (size_t)b * HH + tid]     = h1keep;
    out[base + 2 * (size_t)BB * HH + (size_t)b * HH + tid] = c0;
    out[base + 3 * (size_t)BB * HH + (size_t)b * HH + tid] = c1;
}

extern "C" void kernel_launch(void* const* d_in, const int* in_sizes, int n_in,
                              void* d_out, int out_size, void* d_ws, size_t ws_size,
                              hipStream_t stream) {
    const float* x    = (const float*)d_in[0];
    const float* W_xh = (const float*)d_in[1];
    const float* b_xh = (const float*)d_in[2];
    const float* W_hh = (const float*)d_in[3];
    const float* b_hh = (const float*)d_in[4];
    float* out = (float*)d_out;

    _Float16* wxp = (_Float16*)d_ws;
    _Float16* whp = wxp + 256 * 1024;

    pack_w<<<1024, 256, 0, stream>>>(W_xh, wxp);
    pack_w<<<1024, 256, 0, stream>>>(W_hh, whp);
    lstm_kernel<<<BB, 256, 0, stream>>>(x, b_xh, b_hh, wxp, whp, out);
}

// Round 2
// 10074.226 us; speedup vs baseline: 1.8655x; 1.8655x over previous
//
#include <hip/hip_runtime.h>
#include <hip/hip_fp16.h>

#define BB 64
#define TT 2048
#define DD 256
#define HH 256
#define CHUNK 256
#define NCHUNK 8

typedef _Float16 h2   __attribute__((ext_vector_type(2)));
typedef _Float16 f16x4 __attribute__((ext_vector_type(4)));
typedef _Float16 f16x8 __attribute__((ext_vector_type(8)));

union V8 { f16x8 v; h2 p[4]; };

__device__ __forceinline__ float sigm(float v) {
    return __builtin_amdgcn_rcpf(1.f + __expf(-v));
}
__device__ __forceinline__ float tanh_f(float v) {
    float e = __expf(2.f * v);
    return 1.f - 2.f * __builtin_amdgcn_rcpf(e + 1.f);
}

// Pack W [256][1024] f32 (k-major) into f16 layout [k/8][1024][8]:
// out[((k>>3)*1024 + j)*8 + (k&7)] = (f16) w[k*1024 + j]
__global__ void pack_w(const float* __restrict__ w, _Float16* __restrict__ o) {
    int idx = blockIdx.x * 256 + threadIdx.x;
    int j = idx & 1023;
    int k = idx >> 10;
    o[(((k >> 3) * 1024) + j) * 8 + (k & 7)] = (_Float16)w[idx];
}

// gx = x @ W_xh + b_xh for t in [t0, t0+256), all 64 batches.
// Output layout: gx[b][t-t0][j] f16, [64][256][1024].
// Grid: (16 col-blocks, 256 row-blocks), 256 threads.
__global__ __launch_bounds__(256) void gx_gemm(
    const float* __restrict__ x,
    const _Float16* __restrict__ Wx,   // packed [32][1024][8]
    const float* __restrict__ b_xh,
    _Float16* __restrict__ gx,
    int t0)
{
    __shared__ _Float16 xl[64 * 280];  // 64 rows, stride 280 f16 (560B, 16B-mult)

    const int tid = threadIdx.x;
    const int nb = blockIdx.x;   // col block 0..15
    const int rb = blockIdx.y;   // row block 0..255

    // stage x-tile: 64 rows x 256 k, f32 -> f16
    for (int it = 0; it < 16; ++it) {
        int idx = it * 256 + tid;          // 0..4095 float4s
        int row = idx >> 6, kq = idx & 63;
        int rlin = rb * 64 + row;
        int b = rlin >> 8, tl = rlin & 255;
        float4 v = *(const float4*)&x[((size_t)b * TT + (t0 + tl)) * DD + kq * 4];
        f16x4 h;
        h[0] = (_Float16)v.x; h[1] = (_Float16)v.y;
        h[2] = (_Float16)v.z; h[3] = (_Float16)v.w;
        *(f16x4*)&xl[row * 280 + kq * 4] = h;
    }
    __syncthreads();

    const int ty = tid >> 4, tx = tid & 15;
    const int col0 = nb * 64 + tx * 4;
    const f16x8* __restrict__ wxp = (const f16x8*)Wx;

    float acc[4][4] = {};
#pragma unroll 2
    for (int kk = 0; kk < 32; ++kk) {
        V8 wv[4], xv[4];
#pragma unroll
        for (int c = 0; c < 4; ++c) wv[c].v = wxp[kk * 1024 + col0 + c];
#pragma unroll
        for (int r = 0; r < 4; ++r)
            xv[r].v = *(const f16x8*)&xl[(ty + 16 * r) * 280 + kk * 8];
#pragma unroll
        for (int r = 0; r < 4; ++r)
#pragma unroll
            for (int c = 0; c < 4; ++c)
#pragma unroll
                for (int q = 0; q < 4; ++q)
                    acc[r][c] = __builtin_amdgcn_fdot2(xv[r].p[q], wv[c].p[q], acc[r][c], false);
    }

    float bb[4];
#pragma unroll
    for (int c = 0; c < 4; ++c) bb[c] = b_xh[col0 + c];

#pragma unroll
    for (int r = 0; r < 4; ++r) {
        int rlin = rb * 64 + ty + 16 * r;
        int b = rlin >> 8, tl = rlin & 255;
        f16x4 o;
#pragma unroll
        for (int c = 0; c < 4; ++c) o[c] = (_Float16)(acc[r][c] + bb[c]);
        *(f16x4*)&gx[((size_t)(b * CHUNK + tl)) * 1024 + col0] = o;
    }
}

// Serial recurrence for one chunk of timesteps. 64 blocks (1/batch), 1024 thr.
// Pipeline: phase p does layer0 step t0+p and layer1 step t0+p-1.
__global__ __launch_bounds__(1024) void lstm_serial(
    const _Float16* __restrict__ Wh,   // packed [32][1024][8]
    const float* __restrict__ b_hh,    // [1024]
    const _Float16* __restrict__ gx,   // [64][256][1024] chunk (x@Wx+b_xh)
    float* __restrict__ out,
    float* __restrict__ st,            // h0[16384], h1[16384], c0[16384], c1[16384]
    int t0, int nph, int first, int last)
{
    __shared__ __align__(16) _Float16 h_lds[512];  // h0: [0..255], h1: [256..511]
    __shared__ float g0[1024], g1[1024];

    const int tid = threadIdx.x;
    const int b = blockIdx.x;
    const float bh = b_hh[tid];

    float c_st = 0.f, hkeep = 0.f;
    if (tid < 512) {
        int l = tid >> 8, i = tid & 255;
        if (!first) {
            hkeep = st[l * 16384 + b * 256 + i];
            c_st  = st[(2 + l) * 16384 + b * 256 + i];
        }
        h_lds[tid] = (_Float16)hkeep;
    }
    __syncthreads();

    const f16x8* __restrict__ whp = (const f16x8*)Wh + tid;

    for (int p = 0; p < nph; ++p) {
        const bool l0 = (p < CHUNK);
        const bool l1 = !(first && p == 0);

        float gxv = 0.f;
        if (l0) gxv = (float)gx[((size_t)b * CHUNK + p) * 1024 + tid];

        float d0a = 0.f, d0b = 0.f, d1a = 0.f, d1b = 0.f;
#pragma unroll 4
        for (int kk = 0; kk < 32; ++kk) {
            V8 wv, h0v, h1v;
            wv.v  = whp[kk * 1024];
            h0v.v = *(const f16x8*)&h_lds[kk * 8];
            h1v.v = *(const f16x8*)&h_lds[256 + kk * 8];
            d0a = __builtin_amdgcn_fdot2(h0v.p[0], wv.p[0], d0a, false);
            d0b = __builtin_amdgcn_fdot2(h0v.p[1], wv.p[1], d0b, false);
            d0a = __builtin_amdgcn_fdot2(h0v.p[2], wv.p[2], d0a, false);
            d0b = __builtin_amdgcn_fdot2(h0v.p[3], wv.p[3], d0b, false);
            d1a = __builtin_amdgcn_fdot2(h1v.p[0], wv.p[0], d1a, false);
            d1b = __builtin_amdgcn_fdot2(h1v.p[1], wv.p[1], d1b, false);
            d1a = __builtin_amdgcn_fdot2(h1v.p[2], wv.p[2], d1a, false);
            d1b = __builtin_amdgcn_fdot2(h1v.p[3], wv.p[3], d1b, false);
        }
        float d0 = d0a + d0b;
        float d1 = d1a + d1b;

        g0[tid] = gxv + d0 + bh;          // layer0 gates (gx includes b_xh)
        g1[tid] = d0 + d1 + 2.f * bh;     // layer1 gates
        __syncthreads();

        if (tid < 512) {
            int l = tid >> 8, i = tid & 255;
            bool act = l ? l1 : l0;
            if (act) {
                const float* g = l ? g1 : g0;
                float gi = g[i], gf = g[i + 256], gg = g[i + 512], go = g[i + 768];
                float cn = c_st * sigm(gf) + sigm(gi) * tanh_f(gg);
                float hn = sigm(go) * tanh_f(cn);
                c_st = cn;
                hkeep = hn;
                h_lds[tid] = (_Float16)hn;
                if (l) out[((size_t)b * TT + (t0 + p - 1)) * HH + i] = hn;
            }
        }
        __syncthreads();
    }

    if (tid < 512) {
        int l = tid >> 8, i = tid & 255;
        st[l * 16384 + b * 256 + i] = hkeep;
        st[(2 + l) * 16384 + b * 256 + i] = c_st;
        if (last) {
            size_t base = (size_t)BB * TT * HH;
            out[base + l * 16384 + b * 256 + i] = hkeep;           // h_fin[l]
            out[base + 32768 + l * 16384 + b * 256 + i] = c_st;    // c_fin[l]
        }
    }
}

extern "C" void kernel_launch(void* const* d_in, const int* in_sizes, int n_in,
                              void* d_out, int out_size, void* d_ws, size_t ws_size,
                              hipStream_t stream) {
    const float* x    = (const float*)d_in[0];
    const float* W_xh = (const float*)d_in[1];
    const float* b_xh = (const float*)d_in[2];
    const float* W_hh = (const float*)d_in[3];
    const float* b_hh = (const float*)d_in[4];
    float* out = (float*)d_out;

    char* ws = (char*)d_ws;
    _Float16* wxp = (_Float16*)(ws);                    // 512 KB
    _Float16* whp = (_Float16*)(ws + (512 << 10));      // 512 KB
    float*    st  = (float*)(ws + (1024 << 10));        // 256 KB
    _Float16* gx  = (_Float16*)(ws + (1280 << 10));     // 32 MB

    pack_w<<<1024, 256, 0, stream>>>(W_xh, wxp);
    pack_w<<<1024, 256, 0, stream>>>(W_hh, whp);

    for (int c = 0; c < NCHUNK; ++c) {
        int t0 = c * CHUNK;
        gx_gemm<<<dim3(16, 256), 256, 0, stream>>>(x, wxp, b_xh, gx, t0);
        lstm_serial<<<BB, 1024, 0, stream>>>(whp, b_hh, gx, out, st,
                                             t0, (c == NCHUNK - 1) ? CHUNK + 1 : CHUNK,
                                             c == 0, c == NCHUNK - 1);
    }
}